// Round 1
// baseline (1441.842 us; speedup 1.0000x reference)
//
#include <hip/hip_runtime.h>
#include <stdint.h>

#define LOG_B 18
#define NB (1u << LOG_B)

__device__ __forceinline__ uint32_t mixh(uint32_t v, uint32_t c1, uint32_t c2) {
    v = (v ^ (v >> 16)) * c1;
    v = (v ^ (v >> 13)) * c2;
    return v ^ (v >> 16);
}

// ---- K1: edge scatter-add of two independent 32-bit multiset hashes ----
__global__ void k_edges(const int* __restrict__ row, const int* __restrict__ col,
                        const int* __restrict__ x, uint32_t* __restrict__ sumab, int E) {
    int i = blockIdx.x * blockDim.x + threadIdx.x;
    if (i >= E) return;
    int r = row[i];
    int c = col[i];
    uint32_t v = (uint32_t)x[r];
    uint32_t ha = mixh(v, 0x045D9F3Bu, 0x045D9F3Bu);
    uint32_t hb = mixh(v, 0x9E3779B1u, 0x85EBCA77u);
    atomicAdd(&sumab[2u * (uint32_t)c],     ha);
    atomicAdd(&sumab[2u * (uint32_t)c + 1], hb);
}

// ---- K2: per-node signature + bucket histogram ----
__global__ void k_sig(const int* __restrict__ x, const uint32_t* __restrict__ sumab,
                      unsigned long long* __restrict__ sigs, uint32_t* __restrict__ bcnt, int N) {
    int i = blockIdx.x * blockDim.x + threadIdx.x;
    if (i >= N) return;
    uint32_t v = (uint32_t)x[i];
    uint32_t ha = mixh(v, 0x045D9F3Bu, 0x045D9F3Bu);
    uint32_t hb = mixh(v, 0x9E3779B1u, 0x85EBCA77u);
    uint32_t sa = mixh(ha * 0x27D4EB2Fu + sumab[2 * i],     0xC2B2AE3Du, 0x165667B1u);
    uint32_t sb = mixh(hb * 0x61C88647u + sumab[2 * i + 1], 0x045D9F3Bu, 0x27D4EB2Fu);
    unsigned long long key = ((unsigned long long)sa << 32) | (unsigned long long)sb;
    sigs[i] = key;
    atomicAdd(&bcnt[(uint32_t)(key >> (64 - LOG_B))], 1u);
}

// ---- exclusive scan over NB uint32 (3-kernel hierarchical) ----
__global__ void k_scan1(const uint32_t* __restrict__ in, uint32_t* __restrict__ out,
                        uint32_t* __restrict__ part) {
    __shared__ uint32_t s[1024];
    int t = threadIdx.x;
    int idx = blockIdx.x * 1024 + t;
    uint32_t v = in[idx];
    s[t] = v;
    __syncthreads();
    for (int off = 1; off < 1024; off <<= 1) {
        uint32_t add = (t >= off) ? s[t - off] : 0u;
        __syncthreads();
        s[t] += add;
        __syncthreads();
    }
    out[idx] = s[t] - v;                 // exclusive
    if (t == 1023) part[blockIdx.x] = s[t];
}

__global__ void k_scan2(uint32_t* __restrict__ part) {  // 256 entries, 1 block of 256
    __shared__ uint32_t s[256];
    int t = threadIdx.x;
    uint32_t v = part[t];
    s[t] = v;
    __syncthreads();
    for (int off = 1; off < 256; off <<= 1) {
        uint32_t add = (t >= off) ? s[t - off] : 0u;
        __syncthreads();
        s[t] += add;
        __syncthreads();
    }
    part[t] = s[t] - v;                  // exclusive
}

__global__ void k_scan3(uint32_t* __restrict__ out, const uint32_t* __restrict__ part) {
    int idx = blockIdx.x * 1024 + threadIdx.x;
    out[idx] += part[blockIdx.x];
}

// ---- K3: scatter keys into buckets (order within bucket irrelevant) ----
__global__ void k_scatter(const unsigned long long* __restrict__ sigs,
                          const uint32_t* __restrict__ boff, uint32_t* __restrict__ bcur,
                          unsigned long long* __restrict__ skey, uint32_t* __restrict__ snode,
                          int N) {
    int i = blockIdx.x * blockDim.x + threadIdx.x;
    if (i >= N) return;
    unsigned long long key = sigs[i];
    uint32_t b = (uint32_t)(key >> (64 - LOG_B));
    uint32_t pos = boff[b] + atomicAdd(&bcur[b], 1u);
    skey[pos] = key;
    snode[pos] = (uint32_t)i;
}

// ---- K4: per-bucket insertion sort (48 low bits differ), distinct counts ----
__global__ void k_bsort(unsigned long long* __restrict__ skey, uint32_t* __restrict__ snode,
                        const uint32_t* __restrict__ boff, uint32_t* __restrict__ ldx,
                        uint32_t* __restrict__ dcnt, int N) {
    int b = blockIdx.x * blockDim.x + threadIdx.x;
    if (b >= (int)NB) return;
    uint32_t s0 = boff[b];
    uint32_t s1 = (b == (int)NB - 1) ? (uint32_t)N : boff[b + 1];
    // insertion sort of (key,node) pairs; equal keys cause no shifts -> O(L)
    for (uint32_t i = s0 + 1; i < s1; i++) {
        unsigned long long k = skey[i];
        uint32_t nd = snode[i];
        uint32_t j = i;
        while (j > s0 && skey[j - 1] > k) {
            skey[j] = skey[j - 1];
            snode[j] = snode[j - 1];
            j--;
        }
        skey[j] = k;
        snode[j] = nd;
    }
    // distinct local ranks
    uint32_t d = 0;
    unsigned long long prev = 0ull;
    for (uint32_t i = s0; i < s1; i++) {
        unsigned long long k = skey[i];
        if (i == s0 || k != prev) d++;
        prev = k;
        ldx[i] = d - 1;
    }
    dcnt[b] = d;
}

// ---- K5: final label write ----
__global__ void k_out(const unsigned long long* __restrict__ skey,
                      const uint32_t* __restrict__ snode, const uint32_t* __restrict__ ldx,
                      const uint32_t* __restrict__ doff, int* __restrict__ out, int N) {
    int i = blockIdx.x * blockDim.x + threadIdx.x;
    if (i >= N) return;
    unsigned long long key = skey[i];
    uint32_t b = (uint32_t)(key >> (64 - LOG_B));
    out[snode[i]] = (int)(doff[b] + ldx[i]);
}

extern "C" void kernel_launch(void* const* d_in, const int* in_sizes, int n_in,
                              void* d_out, int out_size, void* d_ws, size_t ws_size,
                              hipStream_t stream) {
    const int* x = (const int*)d_in[0];
    const int* ei = (const int*)d_in[1];
    int N = in_sizes[0];
    int E = in_sizes[1] / 2;
    const int* row = ei;
    const int* col = ei + E;

    char* p = (char*)d_ws;
    auto alloc = [&](size_t bytes) -> char* {
        char* r = p;
        p += (bytes + 255) & ~(size_t)255;
        return r;
    };
    // zero-needing region first (single memsetAsync)
    uint32_t* sumab = (uint32_t*)alloc((size_t)2 * N * 4);
    uint32_t* bcnt  = (uint32_t*)alloc((size_t)NB * 4);
    uint32_t* bcur  = (uint32_t*)alloc((size_t)NB * 4);
    uint32_t* dcnt  = (uint32_t*)alloc((size_t)NB * 4);
    size_t zbytes = (size_t)(p - (char*)d_ws);
    unsigned long long* sigs = (unsigned long long*)alloc((size_t)N * 8);
    unsigned long long* skey = (unsigned long long*)alloc((size_t)N * 8);
    uint32_t* snode = (uint32_t*)alloc((size_t)N * 4);
    uint32_t* ldx   = (uint32_t*)alloc((size_t)N * 4);
    uint32_t* boff  = (uint32_t*)alloc((size_t)NB * 4);
    uint32_t* doff  = (uint32_t*)alloc((size_t)NB * 4);
    uint32_t* part  = (uint32_t*)alloc(256 * 4);

    hipMemsetAsync(d_ws, 0, zbytes, stream);

    int nbN = (N + 255) / 256;
    int nbE = (E + 255) / 256;

    k_edges<<<nbE, 256, 0, stream>>>(row, col, x, sumab, E);
    k_sig<<<nbN, 256, 0, stream>>>(x, sumab, sigs, bcnt, N);

    k_scan1<<<NB / 1024, 1024, 0, stream>>>(bcnt, boff, part);
    k_scan2<<<1, 256, 0, stream>>>(part);
    k_scan3<<<NB / 1024, 1024, 0, stream>>>(boff, part);

    k_scatter<<<nbN, 256, 0, stream>>>(sigs, boff, bcur, skey, snode, N);
    k_bsort<<<NB / 256, 256, 0, stream>>>(skey, snode, boff, ldx, dcnt, N);

    k_scan1<<<NB / 1024, 1024, 0, stream>>>(dcnt, doff, part);
    k_scan2<<<1, 256, 0, stream>>>(part);
    k_scan3<<<NB / 1024, 1024, 0, stream>>>(doff, part);

    k_out<<<nbN, 256, 0, stream>>>(skey, snode, ldx, doff, (int*)d_out, N);
}

// Round 2
// 930.515 us; speedup vs baseline: 1.5495x; 1.5495x over previous
//
#include <hip/hip_runtime.h>
#include <stdint.h>

#define LOG_B 18
#define NB (1u << LOG_B)

__device__ __forceinline__ uint32_t mixh(uint32_t v, uint32_t c1, uint32_t c2) {
    v = (v ^ (v >> 16)) * c1;
    v = (v ^ (v >> 13)) * c2;
    return v ^ (v >> 16);
}

// ---- K1: per-edge packed color-count atomic. counts[node*8 + color/8],
// 8x 8-bit fields per u64. One 64-bit atomic per edge (was two 32-bit). ----
__global__ void k_edges(const int4* __restrict__ row4, const int4* __restrict__ col4,
                        const int* __restrict__ x, unsigned long long* __restrict__ counts,
                        int E4) {
    int i = blockIdx.x * blockDim.x + threadIdx.x;
    if (i >= E4) return;
    int4 r = row4[i];
    int4 c = col4[i];
    {
        uint32_t col = (uint32_t)x[r.x];
        atomicAdd(&counts[8u * (uint32_t)c.x + (col >> 3)], 1ull << (8u * (col & 7u)));
    }
    {
        uint32_t col = (uint32_t)x[r.y];
        atomicAdd(&counts[8u * (uint32_t)c.y + (col >> 3)], 1ull << (8u * (col & 7u)));
    }
    {
        uint32_t col = (uint32_t)x[r.z];
        atomicAdd(&counts[8u * (uint32_t)c.z + (col >> 3)], 1ull << (8u * (col & 7u)));
    }
    {
        uint32_t col = (uint32_t)x[r.w];
        atomicAdd(&counts[8u * (uint32_t)c.w + (col >> 3)], 1ull << (8u * (col & 7u)));
    }
}

// ---- K2: per-node signature from color histogram + bucket histogram ----
__global__ void k_sig(const int* __restrict__ x, const unsigned long long* __restrict__ counts,
                      unsigned long long* __restrict__ sigs, uint32_t* __restrict__ bcnt, int N) {
    __shared__ uint32_t lha[64];
    __shared__ uint32_t lhb[64];
    int t = threadIdx.x;
    if (t < 64) {
        lha[t] = mixh((uint32_t)t, 0x045D9F3Bu, 0x045D9F3Bu);
        lhb[t] = mixh((uint32_t)t, 0x9E3779B1u, 0x85EBCA77u);
    }
    __syncthreads();
    int i = blockIdx.x * blockDim.x + t;
    if (i >= N) return;

    uint32_t sum_a = 0, sum_b = 0;
    const unsigned long long* base = counts + (size_t)i * 8;
#pragma unroll
    for (int w = 0; w < 8; w++) {
        unsigned long long v = base[w];
#pragma unroll
        for (int b = 0; b < 8; b++) {
            uint32_t cnt = (uint32_t)(v >> (8 * b)) & 0xFFu;
            sum_a += cnt * lha[w * 8 + b];
            sum_b += cnt * lhb[w * 8 + b];
        }
    }
    uint32_t v = (uint32_t)x[i];
    uint32_t ha = mixh(v, 0x045D9F3Bu, 0x045D9F3Bu);
    uint32_t hb = mixh(v, 0x9E3779B1u, 0x85EBCA77u);
    uint32_t sa = mixh(ha * 0x27D4EB2Fu + sum_a, 0xC2B2AE3Du, 0x165667B1u);
    uint32_t sb = mixh(hb * 0x61C88647u + sum_b, 0x045D9F3Bu, 0x27D4EB2Fu);
    unsigned long long key = ((unsigned long long)sa << 32) | (unsigned long long)sb;
    sigs[i] = key;
    atomicAdd(&bcnt[(uint32_t)(key >> (64 - LOG_B))], 1u);
}

// ---- exclusive scan over NB uint32 (3-kernel hierarchical) ----
__global__ void k_scan1(const uint32_t* __restrict__ in, uint32_t* __restrict__ out,
                        uint32_t* __restrict__ part) {
    __shared__ uint32_t s[1024];
    int t = threadIdx.x;
    int idx = blockIdx.x * 1024 + t;
    uint32_t v = in[idx];
    s[t] = v;
    __syncthreads();
    for (int off = 1; off < 1024; off <<= 1) {
        uint32_t add = (t >= off) ? s[t - off] : 0u;
        __syncthreads();
        s[t] += add;
        __syncthreads();
    }
    out[idx] = s[t] - v;                 // exclusive
    if (t == 1023) part[blockIdx.x] = s[t];
}

__global__ void k_scan2(uint32_t* __restrict__ part) {  // 256 entries, 1 block of 256
    __shared__ uint32_t s[256];
    int t = threadIdx.x;
    uint32_t v = part[t];
    s[t] = v;
    __syncthreads();
    for (int off = 1; off < 256; off <<= 1) {
        uint32_t add = (t >= off) ? s[t - off] : 0u;
        __syncthreads();
        s[t] += add;
        __syncthreads();
    }
    part[t] = s[t] - v;                  // exclusive
}

__global__ void k_scan3(uint32_t* __restrict__ out, const uint32_t* __restrict__ part) {
    int idx = blockIdx.x * 1024 + threadIdx.x;
    out[idx] += part[blockIdx.x];
}

// ---- K3: scatter keys into buckets (order within bucket irrelevant) ----
__global__ void k_scatter(const unsigned long long* __restrict__ sigs,
                          const uint32_t* __restrict__ boff, uint32_t* __restrict__ bcur,
                          unsigned long long* __restrict__ skey, uint32_t* __restrict__ snode,
                          int N) {
    int i = blockIdx.x * blockDim.x + threadIdx.x;
    if (i >= N) return;
    unsigned long long key = sigs[i];
    uint32_t b = (uint32_t)(key >> (64 - LOG_B));
    uint32_t pos = boff[b] + atomicAdd(&bcur[b], 1u);
    skey[pos] = key;
    snode[pos] = (uint32_t)i;
}

// ---- K4: per-bucket insertion sort, distinct counts ----
__global__ void k_bsort(unsigned long long* __restrict__ skey, uint32_t* __restrict__ snode,
                        const uint32_t* __restrict__ boff, uint32_t* __restrict__ ldx,
                        uint32_t* __restrict__ dcnt, int N) {
    int b = blockIdx.x * blockDim.x + threadIdx.x;
    if (b >= (int)NB) return;
    uint32_t s0 = boff[b];
    uint32_t s1 = (b == (int)NB - 1) ? (uint32_t)N : boff[b + 1];
    for (uint32_t i = s0 + 1; i < s1; i++) {
        unsigned long long k = skey[i];
        uint32_t nd = snode[i];
        uint32_t j = i;
        while (j > s0 && skey[j - 1] > k) {
            skey[j] = skey[j - 1];
            snode[j] = snode[j - 1];
            j--;
        }
        skey[j] = k;
        snode[j] = nd;
    }
    uint32_t d = 0;
    unsigned long long prev = 0ull;
    for (uint32_t i = s0; i < s1; i++) {
        unsigned long long k = skey[i];
        if (i == s0 || k != prev) d++;
        prev = k;
        ldx[i] = d - 1;
    }
    dcnt[b] = d;
}

// ---- K5: final label write ----
__global__ void k_out(const unsigned long long* __restrict__ skey,
                      const uint32_t* __restrict__ snode, const uint32_t* __restrict__ ldx,
                      const uint32_t* __restrict__ doff, int* __restrict__ out, int N) {
    int i = blockIdx.x * blockDim.x + threadIdx.x;
    if (i >= N) return;
    unsigned long long key = skey[i];
    uint32_t b = (uint32_t)(key >> (64 - LOG_B));
    out[snode[i]] = (int)(doff[b] + ldx[i]);
}

extern "C" void kernel_launch(void* const* d_in, const int* in_sizes, int n_in,
                              void* d_out, int out_size, void* d_ws, size_t ws_size,
                              hipStream_t stream) {
    const int* x = (const int*)d_in[0];
    const int* ei = (const int*)d_in[1];
    int N = in_sizes[0];
    int E = in_sizes[1] / 2;
    const int* row = ei;
    const int* col = ei + E;

    char* p = (char*)d_ws;
    auto alloc = [&](size_t bytes) -> char* {
        char* r = p;
        p += (bytes + 255) & ~(size_t)255;
        return r;
    };
    // zero-needing region first (single memsetAsync)
    unsigned long long* counts = (unsigned long long*)alloc((size_t)N * 8 * 8);  // 64B/node
    uint32_t* bcnt  = (uint32_t*)alloc((size_t)NB * 4);
    uint32_t* bcur  = (uint32_t*)alloc((size_t)NB * 4);
    uint32_t* dcnt  = (uint32_t*)alloc((size_t)NB * 4);
    size_t zbytes = (size_t)(p - (char*)d_ws);
    unsigned long long* sigs = (unsigned long long*)alloc((size_t)N * 8);
    unsigned long long* skey = (unsigned long long*)alloc((size_t)N * 8);
    uint32_t* snode = (uint32_t*)alloc((size_t)N * 4);
    uint32_t* ldx   = (uint32_t*)alloc((size_t)N * 4);
    uint32_t* boff  = (uint32_t*)alloc((size_t)NB * 4);
    uint32_t* doff  = (uint32_t*)alloc((size_t)NB * 4);
    uint32_t* part  = (uint32_t*)alloc(256 * 4);

    hipMemsetAsync(d_ws, 0, zbytes, stream);

    int nbN = (N + 255) / 256;
    int E4 = E / 4;                       // E = 16M, divisible by 4
    int nbE = (E4 + 255) / 256;

    k_edges<<<nbE, 256, 0, stream>>>((const int4*)row, (const int4*)col, x, counts, E4);
    k_sig<<<nbN, 256, 0, stream>>>(x, counts, sigs, bcnt, N);

    k_scan1<<<NB / 1024, 1024, 0, stream>>>(bcnt, boff, part);
    k_scan2<<<1, 256, 0, stream>>>(part);
    k_scan3<<<NB / 1024, 1024, 0, stream>>>(boff, part);

    k_scatter<<<nbN, 256, 0, stream>>>(sigs, boff, bcur, skey, snode, N);
    k_bsort<<<NB / 256, 256, 0, stream>>>(skey, snode, boff, ldx, dcnt, N);

    k_scan1<<<NB / 1024, 1024, 0, stream>>>(dcnt, doff, part);
    k_scan2<<<1, 256, 0, stream>>>(part);
    k_scan3<<<NB / 1024, 1024, 0, stream>>>(doff, part);

    k_out<<<nbN, 256, 0, stream>>>(skey, snode, ldx, doff, (int*)d_out, N);
}

// Round 3
// 796.751 us; speedup vs baseline: 1.8097x; 1.1679x over previous
//
#include <hip/hip_runtime.h>
#include <stdint.h>

#define LOG_B 18
#define NB (1u << LOG_B)
#define BKT_NODES 512
#define EPB 32768

__host__ __device__ constexpr uint32_t cmix(uint32_t v, uint32_t c1, uint32_t c2) {
    v = (v ^ (v >> 16)) * c1;
    v = (v ^ (v >> 13)) * c2;
    return v ^ (v >> 16);
}

__device__ __forceinline__ uint32_t mixh(uint32_t v, uint32_t c1, uint32_t c2) {
    v = (v ^ (v >> 16)) * c1;
    v = (v ^ (v >> 13)) * c2;
    return v ^ (v >> 16);
}

struct Luts { uint32_t ha[64]; uint32_t hb[64]; };
constexpr Luts make_luts() {
    Luts l{};
    for (uint32_t i = 0; i < 64; i++) {
        l.ha[i] = cmix(i, 0x045D9F3Bu, 0x045D9F3Bu);
        l.hb[i] = cmix(i, 0x9E3779B1u, 0x85EBCA77u);
    }
    return l;
}
__constant__ Luts LUT = make_luts();

// ---- P1: bin edges by dst bucket. Global atomics: one per (block,bucket). ----
__global__ __launch_bounds__(256) void k_bin(const int* __restrict__ row, const int* __restrict__ col,
                                             const int* __restrict__ x, uint16_t* __restrict__ bins,
                                             uint32_t* __restrict__ cursor, int E, int nbkt, int cap) {
    __shared__ uint32_t hist[1024];
    __shared__ uint32_t gbase[1024];
    int t = threadIdx.x;
    int base = blockIdx.x * EPB;
    for (int b = t; b < nbkt; b += 256) hist[b] = 0;
    __syncthreads();
    int nend = min(E - base, EPB);
    for (int k = t; k < nend; k += 256) {
        uint32_t dst = (uint32_t)col[base + k];
        atomicAdd(&hist[dst >> 9], 1u);
    }
    __syncthreads();
    for (int b = t; b < nbkt; b += 256) {
        uint32_t h = hist[b];
        gbase[b] = h ? atomicAdd(&cursor[b], h) : 0u;
        hist[b] = 0;
    }
    __syncthreads();
    for (int k = t; k < nend; k += 256) {
        int i = base + k;
        uint32_t dst = (uint32_t)col[i];
        uint32_t c = (uint32_t)x[row[i]];
        uint32_t b = dst >> 9;
        uint32_t slot = gbase[b] + atomicAdd(&hist[b], 1u);
        bins[(size_t)b * (uint32_t)cap + slot] = (uint16_t)(((dst & 511u) << 6) | c);
    }
}

// ---- P2: per-bucket color histogram in LDS + fused signature computation ----
__global__ __launch_bounds__(256) void k_accsig(const uint16_t* __restrict__ bins,
                                                const uint32_t* __restrict__ cursor,
                                                const int* __restrict__ x,
                                                unsigned long long* __restrict__ sigs,
                                                uint32_t* __restrict__ bcnt, int N, int cap) {
    __shared__ uint32_t cnt[BKT_NODES * 32];  // 64 KB: u16-pair counters, 64 colors/node
    int t = threadIdx.x;
    int b = blockIdx.x;
    for (int i = t; i < BKT_NODES * 32; i += 256) cnt[i] = 0;
    __syncthreads();
    uint32_t m = cursor[b];
    const uint16_t* mybins = bins + (size_t)b * (uint32_t)cap;
    for (uint32_t k = t; k < m; k += 256) {
        uint32_t rec = mybins[k];
        uint32_t n = rec >> 6, c = rec & 63u;
        atomicAdd(&cnt[n * 32 + (c >> 1)], 1u << (16u * (c & 1u)));
    }
    __syncthreads();
    for (int n = t; n < BKT_NODES; n += 256) {
        int g = b * BKT_NODES + n;
        if (g >= N) break;
        uint32_t sum_a = 0, sum_b = 0;
#pragma unroll
        for (int w = 0; w < 32; w++) {
            uint32_t wp = (uint32_t)(w + n) & 31u;   // skew: conflict-free LDS banks
            uint32_t v = cnt[n * 32 + wp];
            uint32_t lo = v & 0xFFFFu, hi = v >> 16;
            sum_a += lo * LUT.ha[2 * wp] + hi * LUT.ha[2 * wp + 1];
            sum_b += lo * LUT.hb[2 * wp] + hi * LUT.hb[2 * wp + 1];
        }
        uint32_t xv = (uint32_t)x[g];
        uint32_t ha = LUT.ha[xv];
        uint32_t hb = LUT.hb[xv];
        uint32_t sa = mixh(ha * 0x27D4EB2Fu + sum_a, 0xC2B2AE3Du, 0x165667B1u);
        uint32_t sb = mixh(hb * 0x61C88647u + sum_b, 0x045D9F3Bu, 0x27D4EB2Fu);
        unsigned long long key = ((unsigned long long)sa << 32) | (unsigned long long)sb;
        sigs[g] = key;
        atomicAdd(&bcnt[(uint32_t)(key >> (64 - LOG_B))], 1u);
    }
}

// ---- exclusive scan over NB uint32 (3-kernel hierarchical) ----
__global__ void k_scan1(const uint32_t* __restrict__ in, uint32_t* __restrict__ out,
                        uint32_t* __restrict__ part) {
    __shared__ uint32_t s[1024];
    int t = threadIdx.x;
    int idx = blockIdx.x * 1024 + t;
    uint32_t v = in[idx];
    s[t] = v;
    __syncthreads();
    for (int off = 1; off < 1024; off <<= 1) {
        uint32_t add = (t >= off) ? s[t - off] : 0u;
        __syncthreads();
        s[t] += add;
        __syncthreads();
    }
    out[idx] = s[t] - v;                 // exclusive
    if (t == 1023) part[blockIdx.x] = s[t];
}

__global__ void k_scan2(uint32_t* __restrict__ part) {  // 256 entries, 1 block of 256
    __shared__ uint32_t s[256];
    int t = threadIdx.x;
    uint32_t v = part[t];
    s[t] = v;
    __syncthreads();
    for (int off = 1; off < 256; off <<= 1) {
        uint32_t add = (t >= off) ? s[t - off] : 0u;
        __syncthreads();
        s[t] += add;
        __syncthreads();
    }
    part[t] = s[t] - v;                  // exclusive
}

__global__ void k_scan3(uint32_t* __restrict__ out, const uint32_t* __restrict__ part) {
    int idx = blockIdx.x * 1024 + threadIdx.x;
    out[idx] += part[blockIdx.x];
}

// ---- K3: scatter keys into buckets (order within bucket irrelevant) ----
__global__ void k_scatter(const unsigned long long* __restrict__ sigs,
                          const uint32_t* __restrict__ boff, uint32_t* __restrict__ bcur,
                          unsigned long long* __restrict__ skey, uint32_t* __restrict__ snode,
                          int N) {
    int i = blockIdx.x * blockDim.x + threadIdx.x;
    if (i >= N) return;
    unsigned long long key = sigs[i];
    uint32_t b = (uint32_t)(key >> (64 - LOG_B));
    uint32_t pos = boff[b] + atomicAdd(&bcur[b], 1u);
    skey[pos] = key;
    snode[pos] = (uint32_t)i;
}

// ---- K4: per-bucket insertion sort, distinct counts ----
__global__ void k_bsort(unsigned long long* __restrict__ skey, uint32_t* __restrict__ snode,
                        const uint32_t* __restrict__ boff, uint32_t* __restrict__ ldx,
                        uint32_t* __restrict__ dcnt, int N) {
    int b = blockIdx.x * blockDim.x + threadIdx.x;
    if (b >= (int)NB) return;
    uint32_t s0 = boff[b];
    uint32_t s1 = (b == (int)NB - 1) ? (uint32_t)N : boff[b + 1];
    for (uint32_t i = s0 + 1; i < s1; i++) {
        unsigned long long k = skey[i];
        uint32_t nd = snode[i];
        uint32_t j = i;
        while (j > s0 && skey[j - 1] > k) {
            skey[j] = skey[j - 1];
            snode[j] = snode[j - 1];
            j--;
        }
        skey[j] = k;
        snode[j] = nd;
    }
    uint32_t d = 0;
    unsigned long long prev = 0ull;
    for (uint32_t i = s0; i < s1; i++) {
        unsigned long long k = skey[i];
        if (i == s0 || k != prev) d++;
        prev = k;
        ldx[i] = d - 1;
    }
    dcnt[b] = d;
}

// ---- K5: final label write ----
__global__ void k_out(const unsigned long long* __restrict__ skey,
                      const uint32_t* __restrict__ snode, const uint32_t* __restrict__ ldx,
                      const uint32_t* __restrict__ doff, int* __restrict__ out, int N) {
    int i = blockIdx.x * blockDim.x + threadIdx.x;
    if (i >= N) return;
    unsigned long long key = skey[i];
    uint32_t b = (uint32_t)(key >> (64 - LOG_B));
    out[snode[i]] = (int)(doff[b] + ldx[i]);
}

extern "C" void kernel_launch(void* const* d_in, const int* in_sizes, int n_in,
                              void* d_out, int out_size, void* d_ws, size_t ws_size,
                              hipStream_t stream) {
    const int* x = (const int*)d_in[0];
    const int* ei = (const int*)d_in[1];
    int N = in_sizes[0];
    int E = in_sizes[1] / 2;
    const int* row = ei;
    const int* col = ei + E;

    int nbkt = (N + BKT_NODES - 1) / BKT_NODES;          // 977 for N=500k
    int cap = E / nbkt + (E / nbkt) / 16 + 1024;         // mean + ~8 sigma margin
    cap = (cap + 1) & ~1;

    char* p = (char*)d_ws;
    auto alloc = [&](size_t bytes) -> char* {
        char* r = p;
        p += (bytes + 255) & ~(size_t)255;
        return r;
    };
    // zero-needing region first (single memsetAsync)
    uint32_t* cursor = (uint32_t*)alloc(1024 * 4);
    uint32_t* bcnt   = (uint32_t*)alloc((size_t)NB * 4);
    uint32_t* bcur   = (uint32_t*)alloc((size_t)NB * 4);
    uint32_t* dcnt   = (uint32_t*)alloc((size_t)NB * 4);
    size_t zbytes = (size_t)(p - (char*)d_ws);
    unsigned long long* sigs = (unsigned long long*)alloc((size_t)N * 8);
    unsigned long long* skey = (unsigned long long*)alloc((size_t)N * 8);
    uint32_t* snode = (uint32_t*)alloc((size_t)N * 4);
    uint32_t* ldx   = (uint32_t*)alloc((size_t)N * 4);
    uint32_t* boff  = (uint32_t*)alloc((size_t)NB * 4);
    uint32_t* doff  = (uint32_t*)alloc((size_t)NB * 4);
    uint32_t* part  = (uint32_t*)alloc(256 * 4);
    uint16_t* bins  = (uint16_t*)alloc((size_t)nbkt * cap * 2);

    hipMemsetAsync(d_ws, 0, zbytes, stream);

    int nbN = (N + 255) / 256;
    int nbBin = (E + EPB - 1) / EPB;

    k_bin<<<nbBin, 256, 0, stream>>>(row, col, x, bins, cursor, E, nbkt, cap);
    k_accsig<<<nbkt, 256, 0, stream>>>(bins, cursor, x, sigs, bcnt, N, cap);

    k_scan1<<<NB / 1024, 1024, 0, stream>>>(bcnt, boff, part);
    k_scan2<<<1, 256, 0, stream>>>(part);
    k_scan3<<<NB / 1024, 1024, 0, stream>>>(boff, part);

    k_scatter<<<nbN, 256, 0, stream>>>(sigs, boff, bcur, skey, snode, N);
    k_bsort<<<NB / 256, 256, 0, stream>>>(skey, snode, boff, ldx, dcnt, N);

    k_scan1<<<NB / 1024, 1024, 0, stream>>>(dcnt, doff, part);
    k_scan2<<<1, 256, 0, stream>>>(part);
    k_scan3<<<NB / 1024, 1024, 0, stream>>>(doff, part);

    k_out<<<nbN, 256, 0, stream>>>(skey, snode, ldx, doff, (int*)d_out, N);
}

// Round 4
// 736.994 us; speedup vs baseline: 1.9564x; 1.0811x over previous
//
#include <hip/hip_runtime.h>
#include <stdint.h>

#define LOG_B 18
#define NB (1u << LOG_B)
#define BKT_NODES 512
#define EPB 8192

__host__ __device__ constexpr uint32_t cmix(uint32_t v, uint32_t c1, uint32_t c2) {
    v = (v ^ (v >> 16)) * c1;
    v = (v ^ (v >> 13)) * c2;
    return v ^ (v >> 16);
}

__device__ __forceinline__ uint32_t mixh(uint32_t v, uint32_t c1, uint32_t c2) {
    v = (v ^ (v >> 16)) * c1;
    v = (v ^ (v >> 13)) * c2;
    return v ^ (v >> 16);
}

struct Luts { uint32_t ha[64]; uint32_t hb[64]; };
constexpr Luts make_luts() {
    Luts l{};
    for (uint32_t i = 0; i < 64; i++) {
        l.ha[i] = cmix(i, 0x045D9F3Bu, 0x045D9F3Bu);
        l.hb[i] = cmix(i, 0x9E3779B1u, 0x85EBCA77u);
    }
    return l;
}
__constant__ Luts LUT = make_luts();

// ---- P1: bin edges by dst bucket. int4 edge loads; one global atomic per
// (block,bucket) to reserve output runs. EPB=8192 -> 1954 blocks (occupancy). ----
__global__ __launch_bounds__(256) void k_bin(const int* __restrict__ row, const int* __restrict__ col,
                                             const int* __restrict__ x, uint16_t* __restrict__ bins,
                                             uint32_t* __restrict__ cursor, int E, int nbkt, int cap) {
    __shared__ uint32_t hist[1024];
    __shared__ uint32_t gbase[1024];
    int t = threadIdx.x;
    int base = blockIdx.x * EPB;
    int nend = min(E - base, EPB);
    for (int b = t; b < nbkt; b += 256) hist[b] = 0;
    __syncthreads();

    const int4* col4 = (const int4*)(col + base);
    const int4* row4 = (const int4*)(row + base);
    int n4 = nend >> 2;

    for (int k = t; k < n4; k += 256) {
        int4 c = col4[k];
        atomicAdd(&hist[(uint32_t)c.x >> 9], 1u);
        atomicAdd(&hist[(uint32_t)c.y >> 9], 1u);
        atomicAdd(&hist[(uint32_t)c.z >> 9], 1u);
        atomicAdd(&hist[(uint32_t)c.w >> 9], 1u);
    }
    for (int k = (n4 << 2) + t; k < nend; k += 256)
        atomicAdd(&hist[(uint32_t)col[base + k] >> 9], 1u);
    __syncthreads();

    for (int b = t; b < nbkt; b += 256) {
        uint32_t h = hist[b];
        gbase[b] = h ? atomicAdd(&cursor[b], h) : 0u;
        hist[b] = 0;
    }
    __syncthreads();

    for (int k = t; k < n4; k += 256) {
        int4 c = col4[k];
        int4 r = row4[k];
        {
            uint32_t d = (uint32_t)c.x, b = d >> 9;
            uint32_t slot = gbase[b] + atomicAdd(&hist[b], 1u);
            bins[(size_t)b * (uint32_t)cap + slot] = (uint16_t)(((d & 511u) << 6) | (uint32_t)x[r.x]);
        }
        {
            uint32_t d = (uint32_t)c.y, b = d >> 9;
            uint32_t slot = gbase[b] + atomicAdd(&hist[b], 1u);
            bins[(size_t)b * (uint32_t)cap + slot] = (uint16_t)(((d & 511u) << 6) | (uint32_t)x[r.y]);
        }
        {
            uint32_t d = (uint32_t)c.z, b = d >> 9;
            uint32_t slot = gbase[b] + atomicAdd(&hist[b], 1u);
            bins[(size_t)b * (uint32_t)cap + slot] = (uint16_t)(((d & 511u) << 6) | (uint32_t)x[r.z]);
        }
        {
            uint32_t d = (uint32_t)c.w, b = d >> 9;
            uint32_t slot = gbase[b] + atomicAdd(&hist[b], 1u);
            bins[(size_t)b * (uint32_t)cap + slot] = (uint16_t)(((d & 511u) << 6) | (uint32_t)x[r.w]);
        }
    }
    for (int k = (n4 << 2) + t; k < nend; k += 256) {
        int i = base + k;
        uint32_t d = (uint32_t)col[i], b = d >> 9;
        uint32_t slot = gbase[b] + atomicAdd(&hist[b], 1u);
        bins[(size_t)b * (uint32_t)cap + slot] = (uint16_t)(((d & 511u) << 6) | (uint32_t)x[row[i]]);
    }
}

// ---- P2: per-bucket color histogram in LDS + fused signature computation ----
__global__ __launch_bounds__(256) void k_accsig(const uint16_t* __restrict__ bins,
                                                const uint32_t* __restrict__ cursor,
                                                const int* __restrict__ x,
                                                unsigned long long* __restrict__ sigs,
                                                uint32_t* __restrict__ bcnt, int N, int cap) {
    __shared__ uint32_t cnt[BKT_NODES * 32];  // 64 KB: u16-pair counters, 64 colors/node
    int t = threadIdx.x;
    int b = blockIdx.x;
    for (int i = t; i < BKT_NODES * 32; i += 256) cnt[i] = 0;
    __syncthreads();
    uint32_t m = cursor[b];
    const uint16_t* mybins = bins + (size_t)b * (uint32_t)cap;
    for (uint32_t k = t; k < m; k += 256) {
        uint32_t rec = mybins[k];
        uint32_t n = rec >> 6, c = rec & 63u;
        atomicAdd(&cnt[n * 32 + (c >> 1)], 1u << (16u * (c & 1u)));
    }
    __syncthreads();
    for (int n = t; n < BKT_NODES; n += 256) {
        int g = b * BKT_NODES + n;
        if (g >= N) break;
        uint32_t sum_a = 0, sum_b = 0;
#pragma unroll
        for (int w = 0; w < 32; w++) {
            uint32_t wp = (uint32_t)(w + n) & 31u;   // skew: conflict-free LDS banks
            uint32_t v = cnt[n * 32 + wp];
            uint32_t lo = v & 0xFFFFu, hi = v >> 16;
            sum_a += lo * LUT.ha[2 * wp] + hi * LUT.ha[2 * wp + 1];
            sum_b += lo * LUT.hb[2 * wp] + hi * LUT.hb[2 * wp + 1];
        }
        uint32_t xv = (uint32_t)x[g];
        uint32_t ha = LUT.ha[xv];
        uint32_t hb = LUT.hb[xv];
        uint32_t sa = mixh(ha * 0x27D4EB2Fu + sum_a, 0xC2B2AE3Du, 0x165667B1u);
        uint32_t sb = mixh(hb * 0x61C88647u + sum_b, 0x045D9F3Bu, 0x27D4EB2Fu);
        unsigned long long key = ((unsigned long long)sa << 32) | (unsigned long long)sb;
        sigs[g] = key;
        atomicAdd(&bcnt[(uint32_t)(key >> (64 - LOG_B))], 1u);
    }
}

// ---- exclusive scan over NB uint32 (3-kernel hierarchical) ----
__global__ void k_scan1(const uint32_t* __restrict__ in, uint32_t* __restrict__ out,
                        uint32_t* __restrict__ part) {
    __shared__ uint32_t s[1024];
    int t = threadIdx.x;
    int idx = blockIdx.x * 1024 + t;
    uint32_t v = in[idx];
    s[t] = v;
    __syncthreads();
    for (int off = 1; off < 1024; off <<= 1) {
        uint32_t add = (t >= off) ? s[t - off] : 0u;
        __syncthreads();
        s[t] += add;
        __syncthreads();
    }
    out[idx] = s[t] - v;                 // exclusive
    if (t == 1023) part[blockIdx.x] = s[t];
}

__global__ void k_scan2(uint32_t* __restrict__ part) {  // 256 entries, 1 block of 256
    __shared__ uint32_t s[256];
    int t = threadIdx.x;
    uint32_t v = part[t];
    s[t] = v;
    __syncthreads();
    for (int off = 1; off < 256; off <<= 1) {
        uint32_t add = (t >= off) ? s[t - off] : 0u;
        __syncthreads();
        s[t] += add;
        __syncthreads();
    }
    part[t] = s[t] - v;                  // exclusive
}

__global__ void k_scan3(uint32_t* __restrict__ out, const uint32_t* __restrict__ part) {
    int idx = blockIdx.x * 1024 + threadIdx.x;
    out[idx] += part[blockIdx.x];
}

// ---- K3: scatter keys into buckets (order within bucket irrelevant) ----
__global__ void k_scatter(const unsigned long long* __restrict__ sigs,
                          const uint32_t* __restrict__ boff, uint32_t* __restrict__ bcur,
                          unsigned long long* __restrict__ skey, uint32_t* __restrict__ snode,
                          int N) {
    int i = blockIdx.x * blockDim.x + threadIdx.x;
    if (i >= N) return;
    unsigned long long key = sigs[i];
    uint32_t b = (uint32_t)(key >> (64 - LOG_B));
    uint32_t pos = boff[b] + atomicAdd(&bcur[b], 1u);
    skey[pos] = key;
    snode[pos] = (uint32_t)i;
}

// ---- K4: per-bucket insertion sort, distinct counts ----
__global__ void k_bsort(unsigned long long* __restrict__ skey, uint32_t* __restrict__ snode,
                        const uint32_t* __restrict__ boff, uint32_t* __restrict__ ldx,
                        uint32_t* __restrict__ dcnt, int N) {
    int b = blockIdx.x * blockDim.x + threadIdx.x;
    if (b >= (int)NB) return;
    uint32_t s0 = boff[b];
    uint32_t s1 = (b == (int)NB - 1) ? (uint32_t)N : boff[b + 1];
    for (uint32_t i = s0 + 1; i < s1; i++) {
        unsigned long long k = skey[i];
        uint32_t nd = snode[i];
        uint32_t j = i;
        while (j > s0 && skey[j - 1] > k) {
            skey[j] = skey[j - 1];
            snode[j] = snode[j - 1];
            j--;
        }
        skey[j] = k;
        snode[j] = nd;
    }
    uint32_t d = 0;
    unsigned long long prev = 0ull;
    for (uint32_t i = s0; i < s1; i++) {
        unsigned long long k = skey[i];
        if (i == s0 || k != prev) d++;
        prev = k;
        ldx[i] = d - 1;
    }
    dcnt[b] = d;
}

// ---- K5: final label write ----
__global__ void k_out(const unsigned long long* __restrict__ skey,
                      const uint32_t* __restrict__ snode, const uint32_t* __restrict__ ldx,
                      const uint32_t* __restrict__ doff, int* __restrict__ out, int N) {
    int i = blockIdx.x * blockDim.x + threadIdx.x;
    if (i >= N) return;
    unsigned long long key = skey[i];
    uint32_t b = (uint32_t)(key >> (64 - LOG_B));
    out[snode[i]] = (int)(doff[b] + ldx[i]);
}

extern "C" void kernel_launch(void* const* d_in, const int* in_sizes, int n_in,
                              void* d_out, int out_size, void* d_ws, size_t ws_size,
                              hipStream_t stream) {
    const int* x = (const int*)d_in[0];
    const int* ei = (const int*)d_in[1];
    int N = in_sizes[0];
    int E = in_sizes[1] / 2;
    const int* row = ei;
    const int* col = ei + E;

    int nbkt = (N + BKT_NODES - 1) / BKT_NODES;          // 977 for N=500k
    int cap = E / nbkt + (E / nbkt) / 16 + 1024;         // mean + ~8 sigma margin
    cap = (cap + 1) & ~1;

    char* p = (char*)d_ws;
    auto alloc = [&](size_t bytes) -> char* {
        char* r = p;
        p += (bytes + 255) & ~(size_t)255;
        return r;
    };
    // zero-needing region first (single memsetAsync)
    uint32_t* cursor = (uint32_t*)alloc(1024 * 4);
    uint32_t* bcnt   = (uint32_t*)alloc((size_t)NB * 4);
    uint32_t* bcur   = (uint32_t*)alloc((size_t)NB * 4);
    uint32_t* dcnt   = (uint32_t*)alloc((size_t)NB * 4);
    size_t zbytes = (size_t)(p - (char*)d_ws);
    unsigned long long* sigs = (unsigned long long*)alloc((size_t)N * 8);
    unsigned long long* skey = (unsigned long long*)alloc((size_t)N * 8);
    uint32_t* snode = (uint32_t*)alloc((size_t)N * 4);
    uint32_t* ldx   = (uint32_t*)alloc((size_t)N * 4);
    uint32_t* boff  = (uint32_t*)alloc((size_t)NB * 4);
    uint32_t* doff  = (uint32_t*)alloc((size_t)NB * 4);
    uint32_t* part  = (uint32_t*)alloc(256 * 4);
    uint16_t* bins  = (uint16_t*)alloc((size_t)nbkt * cap * 2);

    hipMemsetAsync(d_ws, 0, zbytes, stream);

    int nbN = (N + 255) / 256;
    int nbBin = (E + EPB - 1) / EPB;

    k_bin<<<nbBin, 256, 0, stream>>>(row, col, x, bins, cursor, E, nbkt, cap);
    k_accsig<<<nbkt, 256, 0, stream>>>(bins, cursor, x, sigs, bcnt, N, cap);

    k_scan1<<<NB / 1024, 1024, 0, stream>>>(bcnt, boff, part);
    k_scan2<<<1, 256, 0, stream>>>(part);
    k_scan3<<<NB / 1024, 1024, 0, stream>>>(boff, part);

    k_scatter<<<nbN, 256, 0, stream>>>(sigs, boff, bcur, skey, snode, N);
    k_bsort<<<NB / 256, 256, 0, stream>>>(skey, snode, boff, ldx, dcnt, N);

    k_scan1<<<NB / 1024, 1024, 0, stream>>>(dcnt, doff, part);
    k_scan2<<<1, 256, 0, stream>>>(part);
    k_scan3<<<NB / 1024, 1024, 0, stream>>>(doff, part);

    k_out<<<nbN, 256, 0, stream>>>(skey, snode, ldx, doff, (int*)d_out, N);
}